// Round 6
// baseline (67.953 us; speedup 1.0000x reference)
//
#include <hip/hip_runtime.h>

#define WIN   11
#define IW    512
#define IH    512
#define OW    502         // 512 - 10
#define OH    502
#define NCH   48          // 16*3 channel-images
#define TW    54          // output tile width (valid cols per tile)
#define TH    16          // output tile height
#define SWC   64          // columns computed in V: TW + 10 = 64 = one full wave
#define SWP   66          // LDS row stride in v2f units (g=6 reads up to col 65)
#define SROWS 26          // TH + WIN - 1
#define NGX   10          // ceil(502/54)
#define NGY   32          // ceil(502/16)

typedef float v2f __attribute__((ext_vector_type(2)));

__device__ __forceinline__ float fast_rcp(float x) {
    return __builtin_amdgcn_rcpf(x);   // v_rcp_f32, ~1 ulp
}

// ---- V phase: one streaming step (input row J), all indices compile-time ----
template<bool EDGE, int J>
__device__ __forceinline__ void vstep(const float* __restrict__ p1,
                                      const float* __restrict__ p2,
                                      int y0, int gx,
                                      v2f (&accA)[TH], v2f (&accB)[TH],
                                      const float (&w)[WIN])
{
    int gy = y0 + J;
    if (EDGE) gy = min(gy, IH - 1);
    const int gidx = gy * IW + gx;
    const float av = p1[gidx];
    const float bv = p2[gidx];
    v2f ab; ab.x = av; ab.y = bv;                         // (a, b)
    v2f st; st.x = fmaf(av, av, bv * bv); st.y = av * bv; // (a^2+b^2, ab)
#pragma unroll
    for (int k = 0; k < WIN; ++k) {
        const int r = J - k;                              // compile-time after unroll
        if (r >= 0 && r < TH) {
            v2f ws; ws.x = w[k]; ws.y = w[k];
            accA[r] = __builtin_elementwise_fma(ws, ab, accA[r]);
            accB[r] = __builtin_elementwise_fma(ws, st, accB[r]);
        }
    }
}

template<bool EDGE, int J>
struct VRec {
    static __device__ __forceinline__ void run(const float* __restrict__ p1,
                                               const float* __restrict__ p2,
                                               int y0, int gx,
                                               v2f (&accA)[TH], v2f (&accB)[TH],
                                               const float (&w)[WIN])
    {
        vstep<EDGE, J>(p1, p2, y0, gx, accA, accB, w);
        VRec<EDGE, J + 1>::run(p1, p2, y0, gx, accA, accB, w);
    }
};
template<bool EDGE>
struct VRec<EDGE, SROWS> {
    static __device__ __forceinline__ void run(const float* __restrict__,
                                               const float* __restrict__,
                                               int, int, v2f (&)[TH], v2f (&)[TH],
                                               const float (&)[WIN]) {}
};

template<bool EDGE>
__device__ __forceinline__ void ssim_tile(const float* __restrict__ p1,
                                          const float* __restrict__ p2,
                                          const float (&w)[WIN],
                                          v2f (*vbuf)[TH][SWP],
                                          int x0, int y0, int tid, float& acc)
{
    // ---- Phase V: streaming vertical blur; wave 0 only, one column per lane.
    if (tid < SWC) {
        const int c = tid;
        int gx = x0 + c;
        if (EDGE) gx = min(gx, IW - 1);
        v2f accA[TH], accB[TH];
#pragma unroll
        for (int r = 0; r < TH; ++r) {
            accA[r] = (v2f){0.f, 0.f};
            accB[r] = (v2f){0.f, 0.f};
        }
        VRec<EDGE, 0>::run(p1, p2, y0, gx, accA, accB, w);
#pragma unroll
        for (int r = 0; r < TH; ++r) {
            vbuf[0][r][c] = accA[r];
            vbuf[1][r][c] = accB[r];
        }
    }
    __syncthreads();

    // ---- Phase H: horizontal blur + SSIM. Thread = (row r, x-group g of 8 px).
    const int r  = tid & 15;
    const int g  = tid >> 4;     // 0..7
    const int xs = g * 8;

    if (g < 7) {                 // g=7 would read past SWP and holds no valid px
        v2f resA[8], resB[8];
#pragma unroll
        for (int q = 0; q < 2; ++q) {
            v2f x2[18];
            const float4* src = reinterpret_cast<const float4*>(&vbuf[q][r][xs]);
#pragma unroll
            for (int t = 0; t < 9; ++t) {
                float4 f = src[t];
                x2[2*t+0].x = f.x; x2[2*t+0].y = f.y;
                x2[2*t+1].x = f.z; x2[2*t+1].y = f.w;
            }
#pragma unroll
            for (int o = 0; o < 8; ++o) {
                v2f s = {0.f, 0.f};
#pragma unroll
                for (int k = 0; k < WIN; ++k) {
                    v2f ws; ws.x = w[k]; ws.y = w[k];
                    s = __builtin_elementwise_fma(ws, x2[o + k], s);
                }
                if (q == 0) resA[o] = s; else resB[o] = s;
            }
        }

        const float c1 = 0.0001f;   // (0.01*1.0)^2
        const float c2 = 0.0009f;   // (0.03*1.0)^2
        const int oy = y0 + r;
#pragma unroll
        for (int o = 0; o < 8; ++o) {
            const int tc = xs + o;                 // tile-local column
            bool valid = (tc < TW);                // never emit another tile's px
            if (EDGE) valid = valid && (oy < OH) && ((x0 + tc) < OW);
            if (valid) {
                float m1 = resA[o].x, m2 = resA[o].y;
                float mu11 = m1 * m1, mu22 = m2 * m2, mu12 = m1 * m2;
                float sAB = resB[o].x - mu11 - mu22;   // s11 + s22
                float s12 = resB[o].y - mu12;
                float num = (2.f * mu12 + c1) * (2.f * s12 + c2);
                float den = (mu11 + mu22 + c1) * (sAB + c2);
                acc += num * fast_rcp(den);
            }
        }
    }
}

// Grid: x = 10 x-tiles, y = 32 y-tiles, z = 48 channel-images; 128-thread blocks
__global__ __launch_bounds__(128, 4)
void ssim_fused_kernel(const float* __restrict__ img1,
                       const float* __restrict__ img2,
                       const float* __restrict__ win,
                       float* __restrict__ partial)
{
    __shared__ __align__(16) v2f vbuf[2][TH][SWP];   // 16,896 B
    __shared__ float wavesum[2];

    const int tid = threadIdx.x;
    const int ch = blockIdx.z;
    const int x0 = blockIdx.x * TW;
    const int y0 = blockIdx.y * TH;
    const float* __restrict__ p1 = img1 + (size_t)ch * (IW * IH);
    const float* __restrict__ p2 = img2 + (size_t)ch * (IW * IH);

    float w[WIN];
#pragma unroll
    for (int k = 0; k < WIN; ++k) w[k] = win[k];

    float acc = 0.f;
    const bool edge = (blockIdx.x == gridDim.x - 1) || (blockIdx.y == gridDim.y - 1);
    if (edge) ssim_tile<true >(p1, p2, w, vbuf, x0, y0, tid, acc);
    else      ssim_tile<false>(p1, p2, w, vbuf, x0, y0, tid, acc);

    // ---- block reduction (wave64 shuffle, then 2 wave leaders)
#pragma unroll
    for (int off = 32; off > 0; off >>= 1)
        acc += __shfl_down(acc, off, 64);
    if ((tid & 63) == 0) wavesum[tid >> 6] = acc;
    __syncthreads();
    if (tid == 0) {
        partial[(size_t)blockIdx.z * (gridDim.x * gridDim.y)
                + blockIdx.y * gridDim.x + blockIdx.x] = wavesum[0] + wavesum[1];
    }
}

__global__ __launch_bounds__(256)
void reduce_partials_kernel(const float* __restrict__ partial, int n,
                            float* __restrict__ out, double inv_count)
{
    __shared__ double sd[256];
    double s = 0.0;
    for (int i = threadIdx.x; i < n; i += 256)
        s += (double)partial[i];
    sd[threadIdx.x] = s;
    __syncthreads();
    for (int off = 128; off > 0; off >>= 1) {
        if (threadIdx.x < off) sd[threadIdx.x] += sd[threadIdx.x + off];
        __syncthreads();
    }
    if (threadIdx.x == 0)
        out[0] = (float)(sd[0] * inv_count);
}

extern "C" void kernel_launch(void* const* d_in, const int* in_sizes, int n_in,
                              void* d_out, int out_size, void* d_ws, size_t ws_size,
                              hipStream_t stream)
{
    const float* img1 = (const float*)d_in[0];
    const float* img2 = (const float*)d_in[1];
    const float* win  = (const float*)d_in[2];
    float* out = (float*)d_out;
    float* partial = (float*)d_ws;

    dim3 grid(NGX, NGY, NCH);            // 10 x 32 x 48 = 15360 blocks
    dim3 block(128);

    ssim_fused_kernel<<<grid, block, 0, stream>>>(img1, img2, win, partial);

    const int nblocks = NGX * NGY * NCH;
    const double inv_count = 1.0 / ((double)NCH * OW * OH);
    reduce_partials_kernel<<<1, 256, 0, stream>>>(partial, nblocks, out, inv_count);
}

// Round 7
// 59.904 us; speedup vs baseline: 1.1344x; 1.1344x over previous
//
#include <hip/hip_runtime.h>

#define WIN   11
#define IW    512
#define IH    512
#define OW    502         // 512 - 10
#define OH    502
#define NCH   48          // 16*3 channel-images
#define TW    118         // output tile width (valid cols per tile)
#define TH    16          // output tile height
#define SWC   128         // columns computed in V: TW + 10 = 128 = 2 cols/thread-half
#define SWP   132         // LDS row stride in v2f units (H reads to col 131; 16B align)
#define THALF 8           // output rows per V thread
#define SRH   18          // input rows per V thread (THALF + WIN - 1)
#define NGX   5           // ceil(502/118)
#define NGY   32          // ceil(502/16)

typedef float v2f __attribute__((ext_vector_type(2)));

__device__ __forceinline__ float fast_rcp(float x) {
    return __builtin_amdgcn_rcpf(x);   // v_rcp_f32, ~1 ulp
}

// ---- V phase: one streaming step (input row J), all indices compile-time ----
template<bool EDGE, int J>
__device__ __forceinline__ void vstep(const float* __restrict__ p1,
                                      const float* __restrict__ p2,
                                      int ybase, int gx,
                                      v2f (&accA)[THALF], v2f (&accB)[THALF],
                                      const float (&w)[WIN])
{
    int gy = ybase + J;
    if (EDGE) gy = min(gy, IH - 1);
    const int gidx = gy * IW + gx;
    const float av = p1[gidx];
    const float bv = p2[gidx];
    v2f ab; ab.x = av; ab.y = bv;                         // (a, b)
    v2f st; st.x = fmaf(av, av, bv * bv); st.y = av * bv; // (a^2+b^2, ab)
#pragma unroll
    for (int k = 0; k < WIN; ++k) {
        const int r = J - k;                              // compile-time after unroll
        if (r >= 0 && r < THALF) {
            v2f ws; ws.x = w[k]; ws.y = w[k];
            accA[r] = __builtin_elementwise_fma(ws, ab, accA[r]);
            accB[r] = __builtin_elementwise_fma(ws, st, accB[r]);
        }
    }
}

template<bool EDGE, int J>
struct VRec {
    static __device__ __forceinline__ void run(const float* __restrict__ p1,
                                               const float* __restrict__ p2,
                                               int ybase, int gx,
                                               v2f (&accA)[THALF], v2f (&accB)[THALF],
                                               const float (&w)[WIN])
    {
        vstep<EDGE, J>(p1, p2, ybase, gx, accA, accB, w);
        VRec<EDGE, J + 1>::run(p1, p2, ybase, gx, accA, accB, w);
    }
};
template<bool EDGE>
struct VRec<EDGE, SRH> {
    static __device__ __forceinline__ void run(const float* __restrict__,
                                               const float* __restrict__,
                                               int, int, v2f (&)[THALF], v2f (&)[THALF],
                                               const float (&)[WIN]) {}
};

template<bool EDGE>
__device__ __forceinline__ void ssim_tile(const float* __restrict__ p1,
                                          const float* __restrict__ p2,
                                          const float (&w)[WIN],
                                          v2f (*vbuf)[TH][SWP],
                                          int x0, int y0, int tid, float& acc)
{
    // ---- Phase V: streaming vertical blur; ALL 256 threads, 2 per column.
    // half 0: output rows 0..7 (reads rows 0..17); half 1: rows 8..15 (reads 8..25).
    {
        const int half = tid >> 7;          // 0 or 1
        const int c    = tid & 127;         // column 0..127
        int gx = x0 + c;
        if (EDGE) gx = min(gx, IW - 1);
        const int ybase = y0 + half * THALF;
        v2f accA[THALF], accB[THALF];
#pragma unroll
        for (int r = 0; r < THALF; ++r) {
            accA[r] = (v2f){0.f, 0.f};
            accB[r] = (v2f){0.f, 0.f};
        }
        VRec<EDGE, 0>::run(p1, p2, ybase, gx, accA, accB, w);
        const int rbase = half * THALF;
#pragma unroll
        for (int r = 0; r < THALF; ++r) {
            vbuf[0][rbase + r][c] = accA[r];
            vbuf[1][rbase + r][c] = accB[r];
        }
    }
    __syncthreads();

    // ---- Phase H: horizontal blur + SSIM. Thread = (row r, x-group g of 8 px).
    const int r  = tid & 15;
    const int g  = tid >> 4;     // 0..15
    const int xs = g * 8;

    if (g < 15) {                // 15 groups cover px 0..119 (>= TW=118)
        v2f resA[8], resB[8];
#pragma unroll
        for (int q = 0; q < 2; ++q) {
            v2f x2[18];
            const float4* src = reinterpret_cast<const float4*>(&vbuf[q][r][xs]);
#pragma unroll
            for (int t = 0; t < 9; ++t) {
                float4 f = src[t];
                x2[2*t+0].x = f.x; x2[2*t+0].y = f.y;
                x2[2*t+1].x = f.z; x2[2*t+1].y = f.w;
            }
#pragma unroll
            for (int o = 0; o < 8; ++o) {
                v2f s = {0.f, 0.f};
#pragma unroll
                for (int k = 0; k < WIN; ++k) {
                    v2f ws; ws.x = w[k]; ws.y = w[k];
                    s = __builtin_elementwise_fma(ws, x2[o + k], s);
                }
                if (q == 0) resA[o] = s; else resB[o] = s;
            }
        }

        const float c1 = 0.0001f;   // (0.01*1.0)^2
        const float c2 = 0.0009f;   // (0.03*1.0)^2
        const int oy = y0 + r;
#pragma unroll
        for (int o = 0; o < 8; ++o) {
            const int tc = xs + o;                 // tile-local column
            bool valid = (tc < TW);                // don't emit neighbor tile's px
            if (EDGE) valid = valid && (oy < OH) && ((x0 + tc) < OW);
            if (valid) {
                float m1 = resA[o].x, m2 = resA[o].y;
                float mu11 = m1 * m1, mu22 = m2 * m2, mu12 = m1 * m2;
                float sAB = resB[o].x - mu11 - mu22;   // s11 + s22
                float s12 = resB[o].y - mu12;
                float num = (2.f * mu12 + c1) * (2.f * s12 + c2);
                float den = (mu11 + mu22 + c1) * (sAB + c2);
                acc += num * fast_rcp(den);
            }
        }
    }
}

// Grid: x = 5 x-tiles, y = 32 y-tiles, z = 48 channel-images; 256-thread blocks
__global__ __launch_bounds__(256, 4)
void ssim_fused_kernel(const float* __restrict__ img1,
                       const float* __restrict__ img2,
                       const float* __restrict__ win,
                       float* __restrict__ partial)
{
    __shared__ __align__(16) v2f vbuf[2][TH][SWP];   // 33,792 B -> 4 blocks/CU
    __shared__ float wavesum[4];

    const int tid = threadIdx.x;
    const int ch = blockIdx.z;
    const int x0 = blockIdx.x * TW;
    const int y0 = blockIdx.y * TH;
    const float* __restrict__ p1 = img1 + (size_t)ch * (IW * IH);
    const float* __restrict__ p2 = img2 + (size_t)ch * (IW * IH);

    float w[WIN];
#pragma unroll
    for (int k = 0; k < WIN; ++k) w[k] = win[k];

    float acc = 0.f;
    const bool edge = (blockIdx.x == gridDim.x - 1) || (blockIdx.y == gridDim.y - 1);
    if (edge) ssim_tile<true >(p1, p2, w, vbuf, x0, y0, tid, acc);
    else      ssim_tile<false>(p1, p2, w, vbuf, x0, y0, tid, acc);

    // ---- block reduction (wave64 shuffle, then 4 wave leaders)
#pragma unroll
    for (int off = 32; off > 0; off >>= 1)
        acc += __shfl_down(acc, off, 64);
    if ((tid & 63) == 0) wavesum[tid >> 6] = acc;
    __syncthreads();
    if (tid == 0) {
        partial[(size_t)blockIdx.z * (gridDim.x * gridDim.y)
                + blockIdx.y * gridDim.x + blockIdx.x]
            = wavesum[0] + wavesum[1] + wavesum[2] + wavesum[3];
    }
}

__global__ __launch_bounds__(256)
void reduce_partials_kernel(const float* __restrict__ partial, int n,
                            float* __restrict__ out, double inv_count)
{
    __shared__ double sd[256];
    double s = 0.0;
    for (int i = threadIdx.x; i < n; i += 256)
        s += (double)partial[i];
    sd[threadIdx.x] = s;
    __syncthreads();
    for (int off = 128; off > 0; off >>= 1) {
        if (threadIdx.x < off) sd[threadIdx.x] += sd[threadIdx.x + off];
        __syncthreads();
    }
    if (threadIdx.x == 0)
        out[0] = (float)(sd[0] * inv_count);
}

extern "C" void kernel_launch(void* const* d_in, const int* in_sizes, int n_in,
                              void* d_out, int out_size, void* d_ws, size_t ws_size,
                              hipStream_t stream)
{
    const float* img1 = (const float*)d_in[0];
    const float* img2 = (const float*)d_in[1];
    const float* win  = (const float*)d_in[2];
    float* out = (float*)d_out;
    float* partial = (float*)d_ws;

    dim3 grid(NGX, NGY, NCH);            // 5 x 32 x 48 = 7680 blocks
    dim3 block(256);

    ssim_fused_kernel<<<grid, block, 0, stream>>>(img1, img2, win, partial);

    const int nblocks = NGX * NGY * NCH;
    const double inv_count = 1.0 / ((double)NCH * OW * OH);
    reduce_partials_kernel<<<1, 256, 0, stream>>>(partial, nblocks, out, inv_count);
}